// Round 9
// baseline (400.018 us; speedup 1.0000x reference)
//
#include <hip/hip_runtime.h>
#include <hip/hip_bf16.h>

// GRU2 + FC, r6b: 4-role wave specialization, 16 waves (4/SIMD).
// BUGFIX vs r6: Z-channel scaled by +log2e (not -log2e). With EZ=exp(+sZ),
// h' = (n + EZ*h)/(1+EZ) = (1-z)*n + z*h  (z = EZ/(1+EZ) = sigmoid(sZ)). The
// -log2e version computed z*n+(1-z)*h (swapped).
// role0 (waves 0-3):  L0 MFMA k[0,32)  + ALL L0 activations + h0 write
// role1 (waves 4-7):  L0 MFMA k[32,64) + x-path; writes partials {R,Z,Nh,XN}
// role2 (waves 8-11): L1 MFMA k[0,32)  (ih1+hh1, biases); writes partials
// role3 (waves 12-15):L1 MFMA k[32,64) + ALL L1 activations + h1 write
// Two barriers/step: phase1 (MFMA) | A | phase2 (partial-read + act) | B.
// Layer skew: L1 processes t=i-1 while L0 processes t=i.
// R/N channels pre-scaled by -log2e / -2log2e (exp2 direct); Z by +log2e.
// fp32 accuracy via 3-term bf16 hi/lo compensation (AhiBhi+AloBhi+AhiBlo).
// Layouts (m89-verified): D col=lane&15,row=4*(lane>>4)+reg; A row=lane&15,
// k=8*(lane>>4)+j (+32 for k1 roles); B col=lane&15 same k.

typedef __attribute__((ext_vector_type(8))) __bf16 bf16x8;
typedef __attribute__((ext_vector_type(4))) float f32x4;

#define MFMA16(a, b, c) __builtin_amdgcn_mfma_f32_16x16x32_bf16(a, b, c, 0, 0, 0)

#define T_SZ 256
#define HB   72
#define NLOG2E  (-1.4426950408889634f)
#define PLOG2E  ( 1.4426950408889634f)
#define N2LOG2E (-2.8853900817779268f)

__device__ __forceinline__ void cvt_hilo8(const float* v, bf16x8& hi, bf16x8& lo) {
#pragma unroll
    for (int j = 0; j < 8; ++j) {
        __bf16 h = (__bf16)v[j];
        hi[j] = h;
        lo[j] = (__bf16)(v[j] - (float)h);
    }
}

__device__ __forceinline__ void load_wfrag_s(const float* __restrict__ W, int grow,
                                             int kbase, float scale,
                                             bf16x8& hi, bf16x8& lo) {
    float v[8];
#pragma unroll
    for (int j = 0; j < 8; ++j) v[j] = W[grow * 64 + kbase + j] * scale;
    cvt_hilo8(v, hi, lo);
}

__global__ __launch_bounds__(1024, 4)
void gru2_4ph(const float* __restrict__ x,
              const float* __restrict__ w_ih0, const float* __restrict__ w_hh0,
              const float* __restrict__ b_ih0, const float* __restrict__ b_hh0,
              const float* __restrict__ w_ih1, const float* __restrict__ w_hh1,
              const float* __restrict__ b_ih1, const float* __restrict__ b_hh1,
              const float* __restrict__ fc_w, const float* __restrict__ fc_b,
              float* __restrict__ out)
{
    __shared__ __align__(16) float  xst[T_SZ][4][24];      // 96 KB, x swizzled
    __shared__ __align__(16) __bf16 h0hi[2][16][HB];       // 4.5 KB each
    __shared__ __align__(16) __bf16 h0lo[2][16][HB];
    __shared__ __align__(16) __bf16 h1hi[2][16][HB];
    __shared__ __align__(16) __bf16 h1lo[2][16][HB];
    __shared__ __align__(16) float  pL0[4][4][16][20];     // 20 KB partials L0
    __shared__ __align__(16) float  pL1[4][4][16][20];     // 20 KB partials L1

    const int tid  = threadIdx.x;
    const int lane = tid & 63;
    const int wave = tid >> 6;        // 0..15
    const int role = wave >> 2;       // 0..3
    const int wch  = wave & 3;        // unit chunk
    const int u    = lane & 15;
    const int kq   = lane >> 4;
    const int ug   = wch * 16 + u;    // gate-unit 0..63
    const int rbase = 4 * kq;

    // ---- stage x into swizzled layout: xst[t][rowgroup][(row&3)*5 + d] ----
    {
        const float* xsrc = x + (size_t)blockIdx.x * (16 * 1280);
        for (int idx = tid; idx < 16 * 1280; idx += 1024) {
            int row = idx / 1280;
            int rem = idx - row * 1280;
            int t   = rem / 5;
            int d   = rem - t * 5;
            xst[t][row >> 2][(row & 3) * 5 + d] = xsrc[idx];
        }
        for (int idx = tid; idx < 2 * 16 * HB; idx += 1024) {
            ((__bf16*)h0hi)[idx] = (__bf16)0.0f;
            ((__bf16*)h0lo)[idx] = (__bf16)0.0f;
            ((__bf16*)h1hi)[idx] = (__bf16)0.0f;
            ((__bf16*)h1lo)[idx] = (__bf16)0.0f;
        }
    }
    __syncthreads();

    if (role == 0) {
        // ============ L0 k0 MFMA + L0 activations ============
        bf16x8 wRh, wRl, wZh, wZl, wNh, wNl;
        load_wfrag_s(w_hh0, 0 * 64 + ug, 8 * kq, NLOG2E,  wRh, wRl);
        load_wfrag_s(w_hh0, 1 * 64 + ug, 8 * kq, PLOG2E,  wZh, wZl);
        load_wfrag_s(w_hh0, 2 * 64 + ug, 8 * kq, N2LOG2E, wNh, wNl);
        float h0_own[4] = {0.f, 0.f, 0.f, 0.f};
        f32x4 aR, aZ, aN;
        for (int i = 0; i <= T_SZ; ++i) {
            if (i < T_SZ) {
                const int pr = (i + 1) & 1;             // slot of h0(i-1)
                bf16x8 ah = *(const bf16x8*)&h0hi[pr][u][8 * kq];
                bf16x8 al = *(const bf16x8*)&h0lo[pr][u][8 * kq];
                aR = (f32x4){0.f, 0.f, 0.f, 0.f};
                aZ = (f32x4){0.f, 0.f, 0.f, 0.f};
                aN = (f32x4){0.f, 0.f, 0.f, 0.f};
                __builtin_amdgcn_s_setprio(1);
                aR = MFMA16(ah, wRh, aR); aZ = MFMA16(ah, wZh, aZ); aN = MFMA16(ah, wNh, aN);
                aR = MFMA16(al, wRh, aR); aZ = MFMA16(al, wZh, aZ); aN = MFMA16(al, wNh, aN);
                aR = MFMA16(ah, wRl, aR); aZ = MFMA16(ah, wZl, aZ); aN = MFMA16(ah, wNl, aN);
                __builtin_amdgcn_s_setprio(0);
            }
            __syncthreads();                             // A
            if (i < T_SZ) {
                const f32x4 qR  = *(const f32x4*)&pL0[wch][0][u][rbase];
                const f32x4 qZ  = *(const f32x4*)&pL0[wch][1][u][rbase];
                const f32x4 qNh = *(const f32x4*)&pL0[wch][2][u][rbase];
                const f32x4 qXN = *(const f32x4*)&pL0[wch][3][u][rbase];
                const int ps = i & 1;
#pragma unroll
                for (int r = 0; r < 4; ++r) {
                    float ER = __builtin_amdgcn_exp2f(aR[r] + qR[r]);
                    float rg = __builtin_amdgcn_rcpf(1.0f + ER);
                    float w  = fmaf(rg, aN[r] + qNh[r], qXN[r]);
                    float EN = __builtin_amdgcn_exp2f(w);
                    float n  = (1.0f - EN) * __builtin_amdgcn_rcpf(1.0f + EN);
                    float EZ = __builtin_amdgcn_exp2f(aZ[r] + qZ[r]);
                    float hv = fmaf(EZ, h0_own[r], n) * __builtin_amdgcn_rcpf(1.0f + EZ);
                    h0_own[r] = hv;
                    __bf16 hi = (__bf16)hv;
                    __bf16 lo = (__bf16)(hv - (float)hi);
                    h0hi[ps][rbase + r][ug] = hi;
                    h0lo[ps][rbase + r][ug] = lo;
                }
            }
            __syncthreads();                             // B
        }
    } else if (role == 1) {
        // ============ L0 k1 MFMA + x-path; writes partials ============
        bf16x8 wRh, wRl, wZh, wZl, wNh, wNl;
        load_wfrag_s(w_hh0, 0 * 64 + ug, 32 + 8 * kq, NLOG2E,  wRh, wRl);
        load_wfrag_s(w_hh0, 1 * 64 + ug, 32 + 8 * kq, PLOG2E,  wZh, wZl);
        load_wfrag_s(w_hh0, 2 * 64 + ug, 32 + 8 * kq, N2LOG2E, wNh, wNl);
        float wxr[5], wxz[5], wxn[5];
#pragma unroll
        for (int d = 0; d < 5; ++d) {
            wxr[d] = w_ih0[(0 * 64 + ug) * 5 + d] * NLOG2E;
            wxz[d] = w_ih0[(1 * 64 + ug) * 5 + d] * PLOG2E;
            wxn[d] = w_ih0[(2 * 64 + ug) * 5 + d] * N2LOG2E;
        }
        const float bR0  = (b_ih0[ug] + b_hh0[ug]) * NLOG2E;
        const float bZ0  = (b_ih0[64 + ug] + b_hh0[64 + ug]) * PLOG2E;
        const float bXN0 = b_ih0[128 + ug] * N2LOG2E;
        const float bHN0 = b_hh0[128 + ug] * N2LOG2E;
        for (int i = 0; i <= T_SZ; ++i) {
            if (i < T_SZ) {
                const int pr = (i + 1) & 1;
                bf16x8 ah = *(const bf16x8*)&h0hi[pr][u][32 + 8 * kq];
                bf16x8 al = *(const bf16x8*)&h0lo[pr][u][32 + 8 * kq];
                float xv[20];
                *(float4*)&xv[0]  = *(const float4*)&xst[i][kq][0];
                *(float4*)&xv[4]  = *(const float4*)&xst[i][kq][4];
                *(float4*)&xv[8]  = *(const float4*)&xst[i][kq][8];
                *(float4*)&xv[12] = *(const float4*)&xst[i][kq][12];
                *(float4*)&xv[16] = *(const float4*)&xst[i][kq][16];
                f32x4 aR, aZ, aN, aX;
#pragma unroll
                for (int r = 0; r < 4; ++r) {
                    float vR = bR0, vZ = bZ0, vN = bXN0;
#pragma unroll
                    for (int d = 0; d < 5; ++d) {
                        float x1 = xv[r * 5 + d];
                        vR = fmaf(wxr[d], x1, vR);
                        vZ = fmaf(wxz[d], x1, vZ);
                        vN = fmaf(wxn[d], x1, vN);
                    }
                    aR[r] = vR; aZ[r] = vZ; aX[r] = vN; aN[r] = bHN0;
                }
                __builtin_amdgcn_s_setprio(1);
                aR = MFMA16(ah, wRh, aR); aZ = MFMA16(ah, wZh, aZ); aN = MFMA16(ah, wNh, aN);
                aR = MFMA16(al, wRh, aR); aZ = MFMA16(al, wZh, aZ); aN = MFMA16(al, wNh, aN);
                aR = MFMA16(ah, wRl, aR); aZ = MFMA16(ah, wZl, aZ); aN = MFMA16(ah, wNl, aN);
                __builtin_amdgcn_s_setprio(0);
                *(f32x4*)&pL0[wch][0][u][rbase] = aR;
                *(f32x4*)&pL0[wch][1][u][rbase] = aZ;
                *(f32x4*)&pL0[wch][2][u][rbase] = aN;
                *(f32x4*)&pL0[wch][3][u][rbase] = aX;
            }
            __syncthreads();                             // A
            __syncthreads();                             // B
        }
    } else if (role == 2) {
        // ============ L1 k0 MFMA (ih1 + hh1, with biases); writes partials ====
        bf16x8 iRh, iRl, iZh, iZl, iXh, iXl;
        bf16x8 hRh, hRl, hZh, hZl, hNh, hNl;
        load_wfrag_s(w_ih1, 0 * 64 + ug, 8 * kq, NLOG2E,  iRh, iRl);
        load_wfrag_s(w_ih1, 1 * 64 + ug, 8 * kq, PLOG2E,  iZh, iZl);
        load_wfrag_s(w_ih1, 2 * 64 + ug, 8 * kq, N2LOG2E, iXh, iXl);
        load_wfrag_s(w_hh1, 0 * 64 + ug, 8 * kq, NLOG2E,  hRh, hRl);
        load_wfrag_s(w_hh1, 1 * 64 + ug, 8 * kq, PLOG2E,  hZh, hZl);
        load_wfrag_s(w_hh1, 2 * 64 + ug, 8 * kq, N2LOG2E, hNh, hNl);
        const float bR1 = (b_ih1[ug] + b_hh1[ug]) * NLOG2E;
        const float bZ1 = (b_ih1[64 + ug] + b_hh1[64 + ug]) * PLOG2E;
        const float bX1 = b_ih1[128 + ug] * N2LOG2E;
        const float bN1 = b_hh1[128 + ug] * N2LOG2E;
        for (int i = 0; i <= T_SZ; ++i) {
            if (i >= 1) {
                const int t  = i - 1;
                const int s0 = t & 1;                    // h0(t) slot
                const int s1 = (t + 1) & 1;              // h1(t-1) slot
                bf16x8 a1h = *(const bf16x8*)&h0hi[s0][u][8 * kq];
                bf16x8 a1l = *(const bf16x8*)&h0lo[s0][u][8 * kq];
                bf16x8 a2h = *(const bf16x8*)&h1hi[s1][u][8 * kq];
                bf16x8 a2l = *(const bf16x8*)&h1lo[s1][u][8 * kq];
                f32x4 qR = {bR1, bR1, bR1, bR1};
                f32x4 qZ = {bZ1, bZ1, bZ1, bZ1};
                f32x4 qX = {bX1, bX1, bX1, bX1};
                f32x4 qN = {bN1, bN1, bN1, bN1};
                __builtin_amdgcn_s_setprio(1);
                qR = MFMA16(a1h, iRh, qR); qZ = MFMA16(a1h, iZh, qZ); qX = MFMA16(a1h, iXh, qX);
                qR = MFMA16(a1l, iRh, qR); qZ = MFMA16(a1l, iZh, qZ); qX = MFMA16(a1l, iXh, qX);
                qR = MFMA16(a1h, iRl, qR); qZ = MFMA16(a1h, iZl, qZ); qX = MFMA16(a1h, iXl, qX);
                qR = MFMA16(a2h, hRh, qR); qZ = MFMA16(a2h, hZh, qZ); qN = MFMA16(a2h, hNh, qN);
                qR = MFMA16(a2l, hRh, qR); qZ = MFMA16(a2l, hZh, qZ); qN = MFMA16(a2l, hNh, qN);
                qR = MFMA16(a2h, hRl, qR); qZ = MFMA16(a2h, hZl, qZ); qN = MFMA16(a2h, hNl, qN);
                __builtin_amdgcn_s_setprio(0);
                *(f32x4*)&pL1[wch][0][u][rbase] = qR;
                *(f32x4*)&pL1[wch][1][u][rbase] = qZ;
                *(f32x4*)&pL1[wch][2][u][rbase] = qX;
                *(f32x4*)&pL1[wch][3][u][rbase] = qN;
            }
            __syncthreads();                             // A
            __syncthreads();                             // B
        }
    } else {
        // ============ L1 k1 MFMA + L1 activations ============
        bf16x8 iRh, iRl, iZh, iZl, iXh, iXl;
        bf16x8 hRh, hRl, hZh, hZl, hNh, hNl;
        load_wfrag_s(w_ih1, 0 * 64 + ug, 32 + 8 * kq, NLOG2E,  iRh, iRl);
        load_wfrag_s(w_ih1, 1 * 64 + ug, 32 + 8 * kq, PLOG2E,  iZh, iZl);
        load_wfrag_s(w_ih1, 2 * 64 + ug, 32 + 8 * kq, N2LOG2E, iXh, iXl);
        load_wfrag_s(w_hh1, 0 * 64 + ug, 32 + 8 * kq, NLOG2E,  hRh, hRl);
        load_wfrag_s(w_hh1, 1 * 64 + ug, 32 + 8 * kq, PLOG2E,  hZh, hZl);
        load_wfrag_s(w_hh1, 2 * 64 + ug, 32 + 8 * kq, N2LOG2E, hNh, hNl);
        float h1_own[4] = {0.f, 0.f, 0.f, 0.f};
        f32x4 cR, cZ, cX, cN;
        for (int i = 0; i <= T_SZ; ++i) {
            if (i >= 1) {
                const int t  = i - 1;
                const int s0 = t & 1;
                const int s1 = (t + 1) & 1;
                bf16x8 a1h = *(const bf16x8*)&h0hi[s0][u][32 + 8 * kq];
                bf16x8 a1l = *(const bf16x8*)&h0lo[s0][u][32 + 8 * kq];
                bf16x8 a2h = *(const bf16x8*)&h1hi[s1][u][32 + 8 * kq];
                bf16x8 a2l = *(const bf16x8*)&h1lo[s1][u][32 + 8 * kq];
                cR = (f32x4){0.f, 0.f, 0.f, 0.f};
                cZ = (f32x4){0.f, 0.f, 0.f, 0.f};
                cX = (f32x4){0.f, 0.f, 0.f, 0.f};
                cN = (f32x4){0.f, 0.f, 0.f, 0.f};
                __builtin_amdgcn_s_setprio(1);
                cR = MFMA16(a1h, iRh, cR); cZ = MFMA16(a1h, iZh, cZ); cX = MFMA16(a1h, iXh, cX);
                cR = MFMA16(a1l, iRh, cR); cZ = MFMA16(a1l, iZh, cZ); cX = MFMA16(a1l, iXh, cX);
                cR = MFMA16(a1h, iRl, cR); cZ = MFMA16(a1h, iZl, cZ); cX = MFMA16(a1h, iXl, cX);
                cR = MFMA16(a2h, hRh, cR); cZ = MFMA16(a2h, hZh, cZ); cN = MFMA16(a2h, hNh, cN);
                cR = MFMA16(a2l, hRh, cR); cZ = MFMA16(a2l, hZh, cZ); cN = MFMA16(a2l, hNh, cN);
                cR = MFMA16(a2h, hRl, cR); cZ = MFMA16(a2h, hZl, cZ); cN = MFMA16(a2h, hNl, cN);
                __builtin_amdgcn_s_setprio(0);
            }
            __syncthreads();                             // A
            if (i >= 1) {
                const int t = i - 1;
                const f32x4 qR = *(const f32x4*)&pL1[wch][0][u][rbase];
                const f32x4 qZ = *(const f32x4*)&pL1[wch][1][u][rbase];
                const f32x4 qX = *(const f32x4*)&pL1[wch][2][u][rbase];
                const f32x4 qN = *(const f32x4*)&pL1[wch][3][u][rbase];
                const int ps = t & 1;
#pragma unroll
                for (int r = 0; r < 4; ++r) {
                    float ER = __builtin_amdgcn_exp2f(cR[r] + qR[r]);
                    float rg = __builtin_amdgcn_rcpf(1.0f + ER);
                    float w  = fmaf(rg, cN[r] + qN[r], cX[r] + qX[r]);
                    float EN = __builtin_amdgcn_exp2f(w);
                    float n  = (1.0f - EN) * __builtin_amdgcn_rcpf(1.0f + EN);
                    float EZ = __builtin_amdgcn_exp2f(cZ[r] + qZ[r]);
                    float hv = fmaf(EZ, h1_own[r], n) * __builtin_amdgcn_rcpf(1.0f + EZ);
                    h1_own[r] = hv;
                    __bf16 hi = (__bf16)hv;
                    __bf16 lo = (__bf16)(hv - (float)hi);
                    h1hi[ps][rbase + r][ug] = hi;
                    h1lo[ps][rbase + r][ug] = lo;
                }
            }
            __syncthreads();                             // B
        }
    }

    // ---- FC epilogue: h1(255) in slot 255&1 = 1 ----
    if (tid < 16) {
        float s = fc_b[0];
#pragma unroll 1
        for (int uu = 0; uu < 64; ++uu)
            s = fmaf(fc_w[uu], (float)h1hi[1][tid][uu] + (float)h1lo[1][tid][uu], s);
        out[blockIdx.x * 16 + tid] = s;
    }
}

extern "C" void kernel_launch(void* const* d_in, const int* in_sizes, int n_in,
                              void* d_out, int out_size, void* d_ws, size_t ws_size,
                              hipStream_t stream) {
    const float* x     = (const float*)d_in[0];
    const float* w_ih0 = (const float*)d_in[1];
    const float* w_hh0 = (const float*)d_in[2];
    const float* b_ih0 = (const float*)d_in[3];
    const float* b_hh0 = (const float*)d_in[4];
    const float* w_ih1 = (const float*)d_in[5];
    const float* w_hh1 = (const float*)d_in[6];
    const float* b_ih1 = (const float*)d_in[7];
    const float* b_hh1 = (const float*)d_in[8];
    const float* fc_w  = (const float*)d_in[9];
    const float* fc_b  = (const float*)d_in[10];
    float* out = (float*)d_out;

    gru2_4ph<<<dim3(256), dim3(1024), 0, stream>>>(x, w_ih0, w_hh0, b_ih0, b_hh0,
                                                   w_ih1, w_hh1, b_ih1, b_hh1,
                                                   fc_w, fc_b, out);
}

// Round 10
// 246.378 us; speedup vs baseline: 1.6236x; 1.6236x over previous
//
#include <hip/hip_runtime.h>
#include <hip/hip_bf16.h>

// GRU2 + FC, r8: 12-wave 3-group pipeline (3 waves/SIMD), ONE barrier/step.
// grp0 (waves 0-3):  L0 step i   : x-path + whh0 MFMA(18) + act -> h0(i)
// grp1 (waves 4-7):  L1a step i-1: ih1*h0(t) MFMA(18) -> fp32 partials (LDS)
// grp2 (waves 8-11): L1b step i-2: hh1*h1(t-1) MFMA(18) + partials(t) + act -> h1(t)
// Deep skew: partials written at iter t+1, consumed at iter t+2 -> every
// RAW/WAR crosses the single end-of-iter barrier (parity-checked).
// launch_bounds(768,3): VGPR cap 170 -> no spills (r6b's 26MB scratch was the
// R9 regression). exp2-folded activations (validated R9: Z scaled +log2e).
// fp32 accuracy via 3-term bf16 hi/lo compensation. Layouts m89-verified:
// D col=lane&15,row=4*(lane>>4)+reg; A row=lane&15,k=kk*32+8*(lane>>4)+j.

typedef __attribute__((ext_vector_type(8))) __bf16 bf16x8;
typedef __attribute__((ext_vector_type(4))) float f32x4;

#define MFMA16(a, b, c) __builtin_amdgcn_mfma_f32_16x16x32_bf16(a, b, c, 0, 0, 0)

#define T_SZ 256
#define HB   72
#define NLOG2E  (-1.4426950408889634f)
#define PLOG2E  ( 1.4426950408889634f)
#define N2LOG2E (-2.8853900817779268f)

__device__ __forceinline__ void cvt_hilo8(const float* v, bf16x8& hi, bf16x8& lo) {
#pragma unroll
    for (int j = 0; j < 8; ++j) {
        __bf16 h = (__bf16)v[j];
        hi[j] = h;
        lo[j] = (__bf16)(v[j] - (float)h);
    }
}

__device__ __forceinline__ void load_wfrag_s(const float* __restrict__ W, int grow,
                                             int kbase, float scale,
                                             bf16x8& hi, bf16x8& lo) {
    float v[8];
#pragma unroll
    for (int j = 0; j < 8; ++j) v[j] = W[grow * 64 + kbase + j] * scale;
    cvt_hilo8(v, hi, lo);
}

__global__ __launch_bounds__(768, 3)
void gru2_12w(const float* __restrict__ x,
              const float* __restrict__ w_ih0, const float* __restrict__ w_hh0,
              const float* __restrict__ b_ih0, const float* __restrict__ b_hh0,
              const float* __restrict__ w_ih1, const float* __restrict__ w_hh1,
              const float* __restrict__ b_ih1, const float* __restrict__ b_hh1,
              const float* __restrict__ fc_w, const float* __restrict__ fc_b,
              float* __restrict__ out)
{
    __shared__ __align__(16) float  xst[T_SZ][4][24];     // 96 KB x swizzled
    __shared__ __align__(16) __bf16 h0hi[2][16][HB];      // 4.5 KB each
    __shared__ __align__(16) __bf16 h0lo[2][16][HB];
    __shared__ __align__(16) __bf16 h1hi[2][16][HB];
    __shared__ __align__(16) __bf16 h1lo[2][16][HB];
    __shared__ __align__(16) float  pP[2][3][64][20];     // 30.7 KB partials

    const int tid  = threadIdx.x;
    const int lane = tid & 63;
    const int wave = tid >> 6;        // 0..11
    const int grp  = wave >> 2;       // 0=L0, 1=L1a, 2=L1b
    const int wl   = wave & 3;
    const int u    = lane & 15;
    const int kq   = lane >> 4;
    const int ug   = wl * 16 + u;     // gate-unit 0..63
    const int rbase = 4 * kq;

    // ---- stage x: xst[t][row>>2][(row&3)*5+d]; zero h arrays ----
    {
        const float* xsrc = x + (size_t)blockIdx.x * (16 * 1280);
        for (int idx = tid; idx < 16 * 1280; idx += 768) {
            int row = idx / 1280;
            int rem = idx - row * 1280;
            int t   = rem / 5;
            int d   = rem - t * 5;
            xst[t][row >> 2][(row & 3) * 5 + d] = xsrc[idx];
        }
        for (int idx = tid; idx < 2 * 16 * HB; idx += 768) {
            ((__bf16*)h0hi)[idx] = (__bf16)0.0f;
            ((__bf16*)h0lo)[idx] = (__bf16)0.0f;
            ((__bf16*)h1hi)[idx] = (__bf16)0.0f;
            ((__bf16*)h1lo)[idx] = (__bf16)0.0f;
        }
    }
    __syncthreads();

    if (grp == 0) {
        // =================== L0: full layer-0 step i ===================
        bf16x8 wRh[2], wRl[2], wZh[2], wZl[2], wNh[2], wNl[2];
#pragma unroll
        for (int kk = 0; kk < 2; ++kk) {
            const int kb = kk * 32 + 8 * kq;
            load_wfrag_s(w_hh0, 0 * 64 + ug, kb, NLOG2E,  wRh[kk], wRl[kk]);
            load_wfrag_s(w_hh0, 1 * 64 + ug, kb, PLOG2E,  wZh[kk], wZl[kk]);
            load_wfrag_s(w_hh0, 2 * 64 + ug, kb, N2LOG2E, wNh[kk], wNl[kk]);
        }
        float wxr[5], wxz[5], wxn[5];
#pragma unroll
        for (int d = 0; d < 5; ++d) {
            wxr[d] = w_ih0[(0 * 64 + ug) * 5 + d] * NLOG2E;
            wxz[d] = w_ih0[(1 * 64 + ug) * 5 + d] * PLOG2E;
            wxn[d] = w_ih0[(2 * 64 + ug) * 5 + d] * N2LOG2E;
        }
        const float bR0  = (b_ih0[ug] + b_hh0[ug]) * NLOG2E;
        const float bZ0  = (b_ih0[64 + ug] + b_hh0[64 + ug]) * PLOG2E;
        const float bXN0 = b_ih0[128 + ug] * N2LOG2E;
        const float bHN0 = b_hh0[128 + ug] * N2LOG2E;
        float h0_own[4] = {0.f, 0.f, 0.f, 0.f};

        for (int i = 0; i <= T_SZ + 1; ++i) {
            if (i < T_SZ) {
                const int pr = (i + 1) & 1, ps = i & 1;
                bf16x8 ah[2], al[2];
                ah[0] = *(const bf16x8*)&h0hi[pr][u][8 * kq];
                ah[1] = *(const bf16x8*)&h0hi[pr][u][32 + 8 * kq];
                al[0] = *(const bf16x8*)&h0lo[pr][u][8 * kq];
                al[1] = *(const bf16x8*)&h0lo[pr][u][32 + 8 * kq];
                float xv[20];
                *(float4*)&xv[0]  = *(const float4*)&xst[i][kq][0];
                *(float4*)&xv[4]  = *(const float4*)&xst[i][kq][4];
                *(float4*)&xv[8]  = *(const float4*)&xst[i][kq][8];
                *(float4*)&xv[12] = *(const float4*)&xst[i][kq][12];
                *(float4*)&xv[16] = *(const float4*)&xst[i][kq][16];
                f32x4 aR, aZ, aN;
                float xn0[4];
#pragma unroll
                for (int r = 0; r < 4; ++r) {
                    float vR = bR0, vZ = bZ0, vN = bXN0;
#pragma unroll
                    for (int d = 0; d < 5; ++d) {
                        float x1 = xv[r * 5 + d];
                        vR = fmaf(wxr[d], x1, vR);
                        vZ = fmaf(wxz[d], x1, vZ);
                        vN = fmaf(wxn[d], x1, vN);
                    }
                    aR[r] = vR; aZ[r] = vZ; xn0[r] = vN; aN[r] = bHN0;
                }
                __builtin_amdgcn_s_setprio(1);
#pragma unroll
                for (int kk = 0; kk < 2; ++kk) {
                    aR = MFMA16(ah[kk], wRh[kk], aR);
                    aZ = MFMA16(ah[kk], wZh[kk], aZ);
                    aN = MFMA16(ah[kk], wNh[kk], aN);
                    aR = MFMA16(al[kk], wRh[kk], aR);
                    aZ = MFMA16(al[kk], wZh[kk], aZ);
                    aN = MFMA16(al[kk], wNh[kk], aN);
                    aR = MFMA16(ah[kk], wRl[kk], aR);
                    aZ = MFMA16(ah[kk], wZl[kk], aZ);
                    aN = MFMA16(ah[kk], wNl[kk], aN);
                }
                __builtin_amdgcn_s_setprio(0);
#pragma unroll
                for (int r = 0; r < 4; ++r) {
                    float ER = __builtin_amdgcn_exp2f(aR[r]);
                    float rg = __builtin_amdgcn_rcpf(1.0f + ER);
                    float w  = fmaf(rg, aN[r], xn0[r]);
                    float EN = __builtin_amdgcn_exp2f(w);
                    float n  = (1.0f - EN) * __builtin_amdgcn_rcpf(1.0f + EN);
                    float EZ = __builtin_amdgcn_exp2f(aZ[r]);
                    float hv = fmaf(EZ, h0_own[r], n) * __builtin_amdgcn_rcpf(1.0f + EZ);
                    h0_own[r] = hv;
                    __bf16 hi = (__bf16)hv;
                    __bf16 lo = (__bf16)(hv - (float)hi);
                    h0hi[ps][rbase + r][ug] = hi;
                    h0lo[ps][rbase + r][ug] = lo;
                }
            }
            __syncthreads();
        }
    } else if (grp == 1) {
        // =========== L1a: ih1 * h0(t), t = i-1 -> partials ===========
        bf16x8 iRh[2], iRl[2], iZh[2], iZl[2], iXh[2], iXl[2];
#pragma unroll
        for (int kk = 0; kk < 2; ++kk) {
            const int kb = kk * 32 + 8 * kq;
            load_wfrag_s(w_ih1, 0 * 64 + ug, kb, NLOG2E,  iRh[kk], iRl[kk]);
            load_wfrag_s(w_ih1, 1 * 64 + ug, kb, PLOG2E,  iZh[kk], iZl[kk]);
            load_wfrag_s(w_ih1, 2 * 64 + ug, kb, N2LOG2E, iXh[kk], iXl[kk]);
        }
        const float bR1 = (b_ih1[ug] + b_hh1[ug]) * NLOG2E;
        const float bZ1 = (b_ih1[64 + ug] + b_hh1[64 + ug]) * PLOG2E;
        const float bX1 = b_ih1[128 + ug] * N2LOG2E;

        for (int i = 0; i <= T_SZ + 1; ++i) {
            if (i >= 1 && i <= T_SZ) {
                const int t = i - 1, st = t & 1;
                bf16x8 ah[2], al[2];
                ah[0] = *(const bf16x8*)&h0hi[st][u][8 * kq];
                ah[1] = *(const bf16x8*)&h0hi[st][u][32 + 8 * kq];
                al[0] = *(const bf16x8*)&h0lo[st][u][8 * kq];
                al[1] = *(const bf16x8*)&h0lo[st][u][32 + 8 * kq];
                f32x4 qR = {bR1, bR1, bR1, bR1};
                f32x4 qZ = {bZ1, bZ1, bZ1, bZ1};
                f32x4 qX = {bX1, bX1, bX1, bX1};
                __builtin_amdgcn_s_setprio(1);
#pragma unroll
                for (int kk = 0; kk < 2; ++kk) {
                    qR = MFMA16(ah[kk], iRh[kk], qR);
                    qZ = MFMA16(ah[kk], iZh[kk], qZ);
                    qX = MFMA16(ah[kk], iXh[kk], qX);
                    qR = MFMA16(al[kk], iRh[kk], qR);
                    qZ = MFMA16(al[kk], iZh[kk], qZ);
                    qX = MFMA16(al[kk], iXh[kk], qX);
                    qR = MFMA16(ah[kk], iRl[kk], qR);
                    qZ = MFMA16(ah[kk], iZl[kk], qZ);
                    qX = MFMA16(ah[kk], iXl[kk], qX);
                }
                __builtin_amdgcn_s_setprio(0);
                *(f32x4*)&pP[st][0][ug][rbase] = qR;
                *(f32x4*)&pP[st][1][ug][rbase] = qZ;
                *(f32x4*)&pP[st][2][ug][rbase] = qX;
            }
            __syncthreads();
        }
    } else {
        // ====== L1b: hh1 * h1(t-1) + partials(t) + act, t = i-2 ======
        bf16x8 hRh[2], hRl[2], hZh[2], hZl[2], hNh[2], hNl[2];
#pragma unroll
        for (int kk = 0; kk < 2; ++kk) {
            const int kb = kk * 32 + 8 * kq;
            load_wfrag_s(w_hh1, 0 * 64 + ug, kb, NLOG2E,  hRh[kk], hRl[kk]);
            load_wfrag_s(w_hh1, 1 * 64 + ug, kb, PLOG2E,  hZh[kk], hZl[kk]);
            load_wfrag_s(w_hh1, 2 * 64 + ug, kb, N2LOG2E, hNh[kk], hNl[kk]);
        }
        const float bN1 = b_hh1[128 + ug] * N2LOG2E;
        float h1_own[4] = {0.f, 0.f, 0.f, 0.f};

        for (int i = 0; i <= T_SZ + 1; ++i) {
            if (i >= 2) {
                const int t = i - 2, st = t & 1;
                bf16x8 ah[2], al[2];                     // h1(t-1), slot st^1
                ah[0] = *(const bf16x8*)&h1hi[st ^ 1][u][8 * kq];
                ah[1] = *(const bf16x8*)&h1hi[st ^ 1][u][32 + 8 * kq];
                al[0] = *(const bf16x8*)&h1lo[st ^ 1][u][8 * kq];
                al[1] = *(const bf16x8*)&h1lo[st ^ 1][u][32 + 8 * kq];
                f32x4 cR = {0.f, 0.f, 0.f, 0.f};
                f32x4 cZ = {0.f, 0.f, 0.f, 0.f};
                f32x4 cN = {bN1, bN1, bN1, bN1};
                __builtin_amdgcn_s_setprio(1);
#pragma unroll
                for (int kk = 0; kk < 2; ++kk) {
                    cR = MFMA16(ah[kk], hRh[kk], cR);
                    cZ = MFMA16(ah[kk], hZh[kk], cZ);
                    cN = MFMA16(ah[kk], hNh[kk], cN);
                    cR = MFMA16(al[kk], hRh[kk], cR);
                    cZ = MFMA16(al[kk], hZh[kk], cZ);
                    cN = MFMA16(al[kk], hNh[kk], cN);
                    cR = MFMA16(ah[kk], hRl[kk], cR);
                    cZ = MFMA16(ah[kk], hZl[kk], cZ);
                    cN = MFMA16(ah[kk], hNl[kk], cN);
                }
                __builtin_amdgcn_s_setprio(0);
                const f32x4 qR = *(const f32x4*)&pP[st][0][ug][rbase];
                const f32x4 qZ = *(const f32x4*)&pP[st][1][ug][rbase];
                const f32x4 qX = *(const f32x4*)&pP[st][2][ug][rbase];
#pragma unroll
                for (int r = 0; r < 4; ++r) {
                    float ER = __builtin_amdgcn_exp2f(cR[r] + qR[r]);
                    float rg = __builtin_amdgcn_rcpf(1.0f + ER);
                    float w  = fmaf(rg, cN[r], qX[r]);
                    float EN = __builtin_amdgcn_exp2f(w);
                    float n  = (1.0f - EN) * __builtin_amdgcn_rcpf(1.0f + EN);
                    float EZ = __builtin_amdgcn_exp2f(cZ[r] + qZ[r]);
                    float hv = fmaf(EZ, h1_own[r], n) * __builtin_amdgcn_rcpf(1.0f + EZ);
                    h1_own[r] = hv;
                    __bf16 hi = (__bf16)hv;
                    __bf16 lo = (__bf16)(hv - (float)hi);
                    h1hi[st][rbase + r][ug] = hi;
                    h1lo[st][rbase + r][ug] = lo;
                }
            }
            __syncthreads();
        }
    }

    // ---- FC epilogue: h1(255) in slot 255&1 = 1 ----
    if (tid < 16) {
        float s = fc_b[0];
#pragma unroll 1
        for (int uu = 0; uu < 64; ++uu)
            s = fmaf(fc_w[uu], (float)h1hi[1][tid][uu] + (float)h1lo[1][tid][uu], s);
        out[blockIdx.x * 16 + tid] = s;
    }
}

extern "C" void kernel_launch(void* const* d_in, const int* in_sizes, int n_in,
                              void* d_out, int out_size, void* d_ws, size_t ws_size,
                              hipStream_t stream) {
    const float* x     = (const float*)d_in[0];
    const float* w_ih0 = (const float*)d_in[1];
    const float* w_hh0 = (const float*)d_in[2];
    const float* b_ih0 = (const float*)d_in[3];
    const float* b_hh0 = (const float*)d_in[4];
    const float* w_ih1 = (const float*)d_in[5];
    const float* w_hh1 = (const float*)d_in[6];
    const float* b_ih1 = (const float*)d_in[7];
    const float* b_hh1 = (const float*)d_in[8];
    const float* fc_w  = (const float*)d_in[9];
    const float* fc_b  = (const float*)d_in[10];
    float* out = (float*)d_out;

    gru2_12w<<<dim3(256), dim3(768), 0, stream>>>(x, w_ih0, w_hh0, b_ih0, b_hh0,
                                                  w_ih1, w_hh1, b_ih1, b_hh1,
                                                  fc_w, fc_b, out);
}

// Round 11
// 236.223 us; speedup vs baseline: 1.6934x; 1.0430x over previous
//
#include <hip/hip_runtime.h>
#include <hip/hip_bf16.h>

// GRU2 + FC, r9: r8 (12-wave 3-group pipeline) + latency trims.
// vs r8: (1) __launch_bounds__(768,1) -> VGPR cap 170 (hipcc 2nd arg is
// min-blocks/CU, wave-clamped; (768,3) had silently capped at 85);
// (2) grp0 x-path software-pipelined one step ahead (inits computed in the
// MFMA shadow of the previous step -> off the post-barrier critical path);
// (3) asymmetric setprio: grp1 (feed-forward) runs at prio 0, grp0/grp2
// (recurrence-critical) keep setprio(1) MFMA bursts; grp2 prefetches its
// partial reads before the MFMA burst.
// Structure (r8, validated): grp0 waves 0-3 = L0 step i; grp1 waves 4-7 =
// ih1*h0(t) partials, t=i-1; grp2 waves 8-11 = hh1*h1 + act, t=i-2; ONE
// barrier/step, all RAW/WAR parity-checked. exp2-folded activations
// (Z scaled +log2e). fp32 accuracy via 3-term bf16 hi/lo compensation.
// Layouts m89-verified: D col=lane&15,row=4*(lane>>4)+reg; A row=lane&15,
// k=kk*32+8*(lane>>4)+j.

typedef __attribute__((ext_vector_type(8))) __bf16 bf16x8;
typedef __attribute__((ext_vector_type(4))) float f32x4;

#define MFMA16(a, b, c) __builtin_amdgcn_mfma_f32_16x16x32_bf16(a, b, c, 0, 0, 0)

#define T_SZ 256
#define HB   72
#define NLOG2E  (-1.4426950408889634f)
#define PLOG2E  ( 1.4426950408889634f)
#define N2LOG2E (-2.8853900817779268f)

__device__ __forceinline__ void cvt_hilo8(const float* v, bf16x8& hi, bf16x8& lo) {
#pragma unroll
    for (int j = 0; j < 8; ++j) {
        __bf16 h = (__bf16)v[j];
        hi[j] = h;
        lo[j] = (__bf16)(v[j] - (float)h);
    }
}

__device__ __forceinline__ void load_wfrag_s(const float* __restrict__ W, int grow,
                                             int kbase, float scale,
                                             bf16x8& hi, bf16x8& lo) {
    float v[8];
#pragma unroll
    for (int j = 0; j < 8; ++j) v[j] = W[grow * 64 + kbase + j] * scale;
    cvt_hilo8(v, hi, lo);
}

__global__ __launch_bounds__(768, 1)
void gru2_12w(const float* __restrict__ x,
              const float* __restrict__ w_ih0, const float* __restrict__ w_hh0,
              const float* __restrict__ b_ih0, const float* __restrict__ b_hh0,
              const float* __restrict__ w_ih1, const float* __restrict__ w_hh1,
              const float* __restrict__ b_ih1, const float* __restrict__ b_hh1,
              const float* __restrict__ fc_w, const float* __restrict__ fc_b,
              float* __restrict__ out)
{
    __shared__ __align__(16) float  xst[T_SZ][4][24];     // 96 KB x swizzled
    __shared__ __align__(16) __bf16 h0hi[2][16][HB];      // 4.5 KB each
    __shared__ __align__(16) __bf16 h0lo[2][16][HB];
    __shared__ __align__(16) __bf16 h1hi[2][16][HB];
    __shared__ __align__(16) __bf16 h1lo[2][16][HB];
    __shared__ __align__(16) float  pP[2][3][64][20];     // 30.7 KB partials

    const int tid  = threadIdx.x;
    const int lane = tid & 63;
    const int wave = tid >> 6;        // 0..11
    const int grp  = wave >> 2;       // 0=L0, 1=L1a, 2=L1b
    const int wl   = wave & 3;
    const int u    = lane & 15;
    const int kq   = lane >> 4;
    const int ug   = wl * 16 + u;     // gate-unit 0..63
    const int rbase = 4 * kq;

    // ---- stage x: xst[t][row>>2][(row&3)*5+d]; zero h arrays ----
    {
        const float* xsrc = x + (size_t)blockIdx.x * (16 * 1280);
        for (int idx = tid; idx < 16 * 1280; idx += 768) {
            int row = idx / 1280;
            int rem = idx - row * 1280;
            int t   = rem / 5;
            int d   = rem - t * 5;
            xst[t][row >> 2][(row & 3) * 5 + d] = xsrc[idx];
        }
        for (int idx = tid; idx < 2 * 16 * HB; idx += 768) {
            ((__bf16*)h0hi)[idx] = (__bf16)0.0f;
            ((__bf16*)h0lo)[idx] = (__bf16)0.0f;
            ((__bf16*)h1hi)[idx] = (__bf16)0.0f;
            ((__bf16*)h1lo)[idx] = (__bf16)0.0f;
        }
    }
    __syncthreads();

    if (grp == 0) {
        // =================== L0: full layer-0 step i ===================
        bf16x8 wRh[2], wRl[2], wZh[2], wZl[2], wNh[2], wNl[2];
#pragma unroll
        for (int kk = 0; kk < 2; ++kk) {
            const int kb = kk * 32 + 8 * kq;
            load_wfrag_s(w_hh0, 0 * 64 + ug, kb, NLOG2E,  wRh[kk], wRl[kk]);
            load_wfrag_s(w_hh0, 1 * 64 + ug, kb, PLOG2E,  wZh[kk], wZl[kk]);
            load_wfrag_s(w_hh0, 2 * 64 + ug, kb, N2LOG2E, wNh[kk], wNl[kk]);
        }
        float wxr[5], wxz[5], wxn[5];
#pragma unroll
        for (int d = 0; d < 5; ++d) {
            wxr[d] = w_ih0[(0 * 64 + ug) * 5 + d] * NLOG2E;
            wxz[d] = w_ih0[(1 * 64 + ug) * 5 + d] * PLOG2E;
            wxn[d] = w_ih0[(2 * 64 + ug) * 5 + d] * N2LOG2E;
        }
        const float bR0  = (b_ih0[ug] + b_hh0[ug]) * NLOG2E;
        const float bZ0  = (b_ih0[64 + ug] + b_hh0[64 + ug]) * PLOG2E;
        const float bXN0 = b_ih0[128 + ug] * N2LOG2E;
        const float bHN0 = b_hh0[128 + ug] * N2LOG2E;
        float h0_own[4] = {0.f, 0.f, 0.f, 0.f};

        // software-pipelined x-path: inits for step i computed during step i-1
        f32x4 aR_nx, aZ_nx;
        float xn_nx[4];
        {
            float xv[20];
            *(float4*)&xv[0]  = *(const float4*)&xst[0][kq][0];
            *(float4*)&xv[4]  = *(const float4*)&xst[0][kq][4];
            *(float4*)&xv[8]  = *(const float4*)&xst[0][kq][8];
            *(float4*)&xv[12] = *(const float4*)&xst[0][kq][12];
            *(float4*)&xv[16] = *(const float4*)&xst[0][kq][16];
#pragma unroll
            for (int r = 0; r < 4; ++r) {
                float vR = bR0, vZ = bZ0, vN = bXN0;
#pragma unroll
                for (int d = 0; d < 5; ++d) {
                    float x1 = xv[r * 5 + d];
                    vR = fmaf(wxr[d], x1, vR);
                    vZ = fmaf(wxz[d], x1, vZ);
                    vN = fmaf(wxn[d], x1, vN);
                }
                aR_nx[r] = vR; aZ_nx[r] = vZ; xn_nx[r] = vN;
            }
        }

        for (int i = 0; i <= T_SZ + 1; ++i) {
            if (i < T_SZ) {
                const int pr = (i + 1) & 1, ps = i & 1;
                bf16x8 ah[2], al[2];
                ah[0] = *(const bf16x8*)&h0hi[pr][u][8 * kq];
                ah[1] = *(const bf16x8*)&h0hi[pr][u][32 + 8 * kq];
                al[0] = *(const bf16x8*)&h0lo[pr][u][8 * kq];
                al[1] = *(const bf16x8*)&h0lo[pr][u][32 + 8 * kq];
                f32x4 aR = aR_nx, aZ = aZ_nx;
                f32x4 aN = {bHN0, bHN0, bHN0, bHN0};
                float xn0[4] = {xn_nx[0], xn_nx[1], xn_nx[2], xn_nx[3]};
                __builtin_amdgcn_s_setprio(1);
#pragma unroll
                for (int kk = 0; kk < 2; ++kk) {
                    aR = MFMA16(ah[kk], wRh[kk], aR);
                    aZ = MFMA16(ah[kk], wZh[kk], aZ);
                    aN = MFMA16(ah[kk], wNh[kk], aN);
                    aR = MFMA16(al[kk], wRh[kk], aR);
                    aZ = MFMA16(al[kk], wZh[kk], aZ);
                    aN = MFMA16(al[kk], wNh[kk], aN);
                    aR = MFMA16(ah[kk], wRl[kk], aR);
                    aZ = MFMA16(ah[kk], wZl[kk], aZ);
                    aN = MFMA16(ah[kk], wNl[kk], aN);
                }
                __builtin_amdgcn_s_setprio(0);
                // next step's x-path in the MFMA shadow
                if (i + 1 < T_SZ) {
                    float xv[20];
                    *(float4*)&xv[0]  = *(const float4*)&xst[i + 1][kq][0];
                    *(float4*)&xv[4]  = *(const float4*)&xst[i + 1][kq][4];
                    *(float4*)&xv[8]  = *(const float4*)&xst[i + 1][kq][8];
                    *(float4*)&xv[12] = *(const float4*)&xst[i + 1][kq][12];
                    *(float4*)&xv[16] = *(const float4*)&xst[i + 1][kq][16];
#pragma unroll
                    for (int r = 0; r < 4; ++r) {
                        float vR = bR0, vZ = bZ0, vN = bXN0;
#pragma unroll
                        for (int d = 0; d < 5; ++d) {
                            float x1 = xv[r * 5 + d];
                            vR = fmaf(wxr[d], x1, vR);
                            vZ = fmaf(wxz[d], x1, vZ);
                            vN = fmaf(wxn[d], x1, vN);
                        }
                        aR_nx[r] = vR; aZ_nx[r] = vZ; xn_nx[r] = vN;
                    }
                }
#pragma unroll
                for (int r = 0; r < 4; ++r) {
                    float ER = __builtin_amdgcn_exp2f(aR[r]);
                    float rg = __builtin_amdgcn_rcpf(1.0f + ER);
                    float w  = fmaf(rg, aN[r], xn0[r]);
                    float EN = __builtin_amdgcn_exp2f(w);
                    float n  = (1.0f - EN) * __builtin_amdgcn_rcpf(1.0f + EN);
                    float EZ = __builtin_amdgcn_exp2f(aZ[r]);
                    float hv = fmaf(EZ, h0_own[r], n) * __builtin_amdgcn_rcpf(1.0f + EZ);
                    h0_own[r] = hv;
                    __bf16 hi = (__bf16)hv;
                    __bf16 lo = (__bf16)(hv - (float)hi);
                    h0hi[ps][rbase + r][ug] = hi;
                    h0lo[ps][rbase + r][ug] = lo;
                }
            }
            __syncthreads();
        }
    } else if (grp == 1) {
        // =========== L1a: ih1 * h0(t), t = i-1 -> partials (prio 0) ===========
        bf16x8 iRh[2], iRl[2], iZh[2], iZl[2], iXh[2], iXl[2];
#pragma unroll
        for (int kk = 0; kk < 2; ++kk) {
            const int kb = kk * 32 + 8 * kq;
            load_wfrag_s(w_ih1, 0 * 64 + ug, kb, NLOG2E,  iRh[kk], iRl[kk]);
            load_wfrag_s(w_ih1, 1 * 64 + ug, kb, PLOG2E,  iZh[kk], iZl[kk]);
            load_wfrag_s(w_ih1, 2 * 64 + ug, kb, N2LOG2E, iXh[kk], iXl[kk]);
        }
        const float bR1 = (b_ih1[ug] + b_hh1[ug]) * NLOG2E;
        const float bZ1 = (b_ih1[64 + ug] + b_hh1[64 + ug]) * PLOG2E;
        const float bX1 = b_ih1[128 + ug] * N2LOG2E;

        for (int i = 0; i <= T_SZ + 1; ++i) {
            if (i >= 1 && i <= T_SZ) {
                const int t = i - 1, st = t & 1;
                bf16x8 ah[2], al[2];
                ah[0] = *(const bf16x8*)&h0hi[st][u][8 * kq];
                ah[1] = *(const bf16x8*)&h0hi[st][u][32 + 8 * kq];
                al[0] = *(const bf16x8*)&h0lo[st][u][8 * kq];
                al[1] = *(const bf16x8*)&h0lo[st][u][32 + 8 * kq];
                f32x4 qR = {bR1, bR1, bR1, bR1};
                f32x4 qZ = {bZ1, bZ1, bZ1, bZ1};
                f32x4 qX = {bX1, bX1, bX1, bX1};
#pragma unroll
                for (int kk = 0; kk < 2; ++kk) {
                    qR = MFMA16(ah[kk], iRh[kk], qR);
                    qZ = MFMA16(ah[kk], iZh[kk], qZ);
                    qX = MFMA16(ah[kk], iXh[kk], qX);
                    qR = MFMA16(al[kk], iRh[kk], qR);
                    qZ = MFMA16(al[kk], iZh[kk], qZ);
                    qX = MFMA16(al[kk], iXh[kk], qX);
                    qR = MFMA16(ah[kk], iRl[kk], qR);
                    qZ = MFMA16(ah[kk], iZl[kk], qZ);
                    qX = MFMA16(ah[kk], iXl[kk], qX);
                }
                *(f32x4*)&pP[st][0][ug][rbase] = qR;
                *(f32x4*)&pP[st][1][ug][rbase] = qZ;
                *(f32x4*)&pP[st][2][ug][rbase] = qX;
            }
            __syncthreads();
        }
    } else {
        // ====== L1b: hh1 * h1(t-1) + partials(t) + act, t = i-2 ======
        bf16x8 hRh[2], hRl[2], hZh[2], hZl[2], hNh[2], hNl[2];
#pragma unroll
        for (int kk = 0; kk < 2; ++kk) {
            const int kb = kk * 32 + 8 * kq;
            load_wfrag_s(w_hh1, 0 * 64 + ug, kb, NLOG2E,  hRh[kk], hRl[kk]);
            load_wfrag_s(w_hh1, 1 * 64 + ug, kb, PLOG2E,  hZh[kk], hZl[kk]);
            load_wfrag_s(w_hh1, 2 * 64 + ug, kb, N2LOG2E, hNh[kk], hNl[kk]);
        }
        const float bN1 = b_hh1[128 + ug] * N2LOG2E;
        float h1_own[4] = {0.f, 0.f, 0.f, 0.f};

        for (int i = 0; i <= T_SZ + 1; ++i) {
            if (i >= 2) {
                const int t = i - 2, st = t & 1;
                bf16x8 ah[2], al[2];                     // h1(t-1), slot st^1
                ah[0] = *(const bf16x8*)&h1hi[st ^ 1][u][8 * kq];
                ah[1] = *(const bf16x8*)&h1hi[st ^ 1][u][32 + 8 * kq];
                al[0] = *(const bf16x8*)&h1lo[st ^ 1][u][8 * kq];
                al[1] = *(const bf16x8*)&h1lo[st ^ 1][u][32 + 8 * kq];
                // prefetch partials (written last interval, ready now)
                const f32x4 qR = *(const f32x4*)&pP[st][0][ug][rbase];
                const f32x4 qZ = *(const f32x4*)&pP[st][1][ug][rbase];
                const f32x4 qX = *(const f32x4*)&pP[st][2][ug][rbase];
                f32x4 cR = {0.f, 0.f, 0.f, 0.f};
                f32x4 cZ = {0.f, 0.f, 0.f, 0.f};
                f32x4 cN = {bN1, bN1, bN1, bN1};
                __builtin_amdgcn_s_setprio(1);
#pragma unroll
                for (int kk = 0; kk < 2; ++kk) {
                    cR = MFMA16(ah[kk], hRh[kk], cR);
                    cZ = MFMA16(ah[kk], hZh[kk], cZ);
                    cN = MFMA16(ah[kk], hNh[kk], cN);
                    cR = MFMA16(al[kk], hRh[kk], cR);
                    cZ = MFMA16(al[kk], hZh[kk], cZ);
                    cN = MFMA16(al[kk], hNh[kk], cN);
                    cR = MFMA16(ah[kk], hRl[kk], cR);
                    cZ = MFMA16(ah[kk], hZl[kk], cZ);
                    cN = MFMA16(ah[kk], hNl[kk], cN);
                }
                __builtin_amdgcn_s_setprio(0);
#pragma unroll
                for (int r = 0; r < 4; ++r) {
                    float ER = __builtin_amdgcn_exp2f(cR[r] + qR[r]);
                    float rg = __builtin_amdgcn_rcpf(1.0f + ER);
                    float w  = fmaf(rg, cN[r], qX[r]);
                    float EN = __builtin_amdgcn_exp2f(w);
                    float n  = (1.0f - EN) * __builtin_amdgcn_rcpf(1.0f + EN);
                    float EZ = __builtin_amdgcn_exp2f(cZ[r] + qZ[r]);
                    float hv = fmaf(EZ, h1_own[r], n) * __builtin_amdgcn_rcpf(1.0f + EZ);
                    h1_own[r] = hv;
                    __bf16 hi = (__bf16)hv;
                    __bf16 lo = (__bf16)(hv - (float)hi);
                    h1hi[st][rbase + r][ug] = hi;
                    h1lo[st][rbase + r][ug] = lo;
                }
            }
            __syncthreads();
        }
    }

    // ---- FC epilogue: h1(255) in slot 255&1 = 1 ----
    if (tid < 16) {
        float s = fc_b[0];
#pragma unroll 1
        for (int uu = 0; uu < 64; ++uu)
            s = fmaf(fc_w[uu], (float)h1hi[1][tid][uu] + (float)h1lo[1][tid][uu], s);
        out[blockIdx.x * 16 + tid] = s;
    }
}

extern "C" void kernel_launch(void* const* d_in, const int* in_sizes, int n_in,
                              void* d_out, int out_size, void* d_ws, size_t ws_size,
                              hipStream_t stream) {
    const float* x     = (const float*)d_in[0];
    const float* w_ih0 = (const float*)d_in[1];
    const float* w_hh0 = (const float*)d_in[2];
    const float* b_ih0 = (const float*)d_in[3];
    const float* b_hh0 = (const float*)d_in[4];
    const float* w_ih1 = (const float*)d_in[5];
    const float* w_hh1 = (const float*)d_in[6];
    const float* b_ih1 = (const float*)d_in[7];
    const float* b_hh1 = (const float*)d_in[8];
    const float* fc_w  = (const float*)d_in[9];
    const float* fc_b  = (const float*)d_in[10];
    float* out = (float*)d_out;

    gru2_12w<<<dim3(256), dim3(768), 0, stream>>>(x, w_ih0, w_hh0, b_ih0, b_hh0,
                                                  w_ih1, w_hh1, b_ih1, b_hh1,
                                                  fc_w, fc_b, out);
}

// Round 12
// 214.969 us; speedup vs baseline: 1.8608x; 1.0989x over previous
//
#include <hip/hip_runtime.h>
#include <hip/hip_bf16.h>

// GRU2 + FC, r10: r9 structure + f16 2-term compensation (was bf16 3-term).
// MFMA per wave-step 18 -> 12: product = (Ahi+Alo)*Bhi exact in f16;
// dropped h*Blo error ~5e-5 RMS/step (f16 ulp on |w|<=0.18) -> absmax ~3-6e-4.
// Weight-lo fragments deleted (-24 VGPR grp0). tanh = 2*rcp(1+EN)-1.
// Structure (r8/r9, validated): 12 waves, 3 groups, ONE barrier/step:
// grp0 waves 0-3: L0 step i (x-path pipelined in MFMA shadow + act + h0);
// grp1 waves 4-7: ih1*h0(t) t=i-1 -> f32 partials (prio 0);
// grp2 waves 8-11: hh1*h1(t-1) + partials + act -> h1, t=i-2.
// All RAW/WAR parity-checked across the single barrier. exp2-folded
// activations (R,N x -log2e/-2log2e; Z x +log2e). Layouts m89-verified
// (shape-determined, dtype-independent): D col=lane&15,row=4*(lane>>4)+reg;
// A row=lane&15, k=kk*32+8*(lane>>4)+j; B col=lane&15 same k.

typedef __attribute__((ext_vector_type(8))) _Float16 f16x8;
typedef __attribute__((ext_vector_type(4))) float f32x4;

#define MFMA16(a, b, c) __builtin_amdgcn_mfma_f32_16x16x32_f16(a, b, c, 0, 0, 0)

#define T_SZ 256
#define HB   72
#define NLOG2E  (-1.4426950408889634f)
#define PLOG2E  ( 1.4426950408889634f)
#define N2LOG2E (-2.8853900817779268f)

__device__ __forceinline__ void load_wfrag_hi(const float* __restrict__ W, int grow,
                                              int kbase, float scale, f16x8& hi) {
#pragma unroll
    for (int j = 0; j < 8; ++j)
        hi[j] = (_Float16)(W[grow * 64 + kbase + j] * scale);
}

__global__ __launch_bounds__(768, 1)
void gru2_f16(const float* __restrict__ x,
              const float* __restrict__ w_ih0, const float* __restrict__ w_hh0,
              const float* __restrict__ b_ih0, const float* __restrict__ b_hh0,
              const float* __restrict__ w_ih1, const float* __restrict__ w_hh1,
              const float* __restrict__ b_ih1, const float* __restrict__ b_hh1,
              const float* __restrict__ fc_w, const float* __restrict__ fc_b,
              float* __restrict__ out)
{
    __shared__ __align__(16) float    xst[T_SZ][4][24];   // 96 KB x swizzled
    __shared__ __align__(16) _Float16 h0hi[2][16][HB];    // 4.5 KB each
    __shared__ __align__(16) _Float16 h0lo[2][16][HB];
    __shared__ __align__(16) _Float16 h1hi[2][16][HB];
    __shared__ __align__(16) _Float16 h1lo[2][16][HB];
    __shared__ __align__(16) float    pP[2][3][64][20];   // 30.7 KB partials

    const int tid  = threadIdx.x;
    const int lane = tid & 63;
    const int wave = tid >> 6;        // 0..11
    const int grp  = wave >> 2;       // 0=L0, 1=L1a, 2=L1b
    const int wl   = wave & 3;
    const int u    = lane & 15;
    const int kq   = lane >> 4;
    const int ug   = wl * 16 + u;     // gate-unit 0..63
    const int rbase = 4 * kq;

    // ---- stage x: xst[t][row>>2][(row&3)*5+d]; zero h arrays ----
    {
        const float* xsrc = x + (size_t)blockIdx.x * (16 * 1280);
        for (int idx = tid; idx < 16 * 1280; idx += 768) {
            int row = idx / 1280;
            int rem = idx - row * 1280;
            int t   = rem / 5;
            int d   = rem - t * 5;
            xst[t][row >> 2][(row & 3) * 5 + d] = xsrc[idx];
        }
        for (int idx = tid; idx < 2 * 16 * HB; idx += 768) {
            ((_Float16*)h0hi)[idx] = (_Float16)0.0f;
            ((_Float16*)h0lo)[idx] = (_Float16)0.0f;
            ((_Float16*)h1hi)[idx] = (_Float16)0.0f;
            ((_Float16*)h1lo)[idx] = (_Float16)0.0f;
        }
    }
    __syncthreads();

    if (grp == 0) {
        // =================== L0: full layer-0 step i ===================
        f16x8 wR[2], wZ[2], wN[2];
#pragma unroll
        for (int kk = 0; kk < 2; ++kk) {
            const int kb = kk * 32 + 8 * kq;
            load_wfrag_hi(w_hh0, 0 * 64 + ug, kb, NLOG2E,  wR[kk]);
            load_wfrag_hi(w_hh0, 1 * 64 + ug, kb, PLOG2E,  wZ[kk]);
            load_wfrag_hi(w_hh0, 2 * 64 + ug, kb, N2LOG2E, wN[kk]);
        }
        float wxr[5], wxz[5], wxn[5];
#pragma unroll
        for (int d = 0; d < 5; ++d) {
            wxr[d] = w_ih0[(0 * 64 + ug) * 5 + d] * NLOG2E;
            wxz[d] = w_ih0[(1 * 64 + ug) * 5 + d] * PLOG2E;
            wxn[d] = w_ih0[(2 * 64 + ug) * 5 + d] * N2LOG2E;
        }
        const float bR0  = (b_ih0[ug] + b_hh0[ug]) * NLOG2E;
        const float bZ0  = (b_ih0[64 + ug] + b_hh0[64 + ug]) * PLOG2E;
        const float bXN0 = b_ih0[128 + ug] * N2LOG2E;
        const float bHN0 = b_hh0[128 + ug] * N2LOG2E;
        float h0_own[4] = {0.f, 0.f, 0.f, 0.f};

        // software-pipelined x-path: inits for step i computed during step i-1
        f32x4 aR_nx, aZ_nx;
        float xn_nx[4];
        {
            float xv[20];
            *(float4*)&xv[0]  = *(const float4*)&xst[0][kq][0];
            *(float4*)&xv[4]  = *(const float4*)&xst[0][kq][4];
            *(float4*)&xv[8]  = *(const float4*)&xst[0][kq][8];
            *(float4*)&xv[12] = *(const float4*)&xst[0][kq][12];
            *(float4*)&xv[16] = *(const float4*)&xst[0][kq][16];
#pragma unroll
            for (int r = 0; r < 4; ++r) {
                float vR = bR0, vZ = bZ0, vN = bXN0;
#pragma unroll
                for (int d = 0; d < 5; ++d) {
                    float x1 = xv[r * 5 + d];
                    vR = fmaf(wxr[d], x1, vR);
                    vZ = fmaf(wxz[d], x1, vZ);
                    vN = fmaf(wxn[d], x1, vN);
                }
                aR_nx[r] = vR; aZ_nx[r] = vZ; xn_nx[r] = vN;
            }
        }

        for (int i = 0; i <= T_SZ + 1; ++i) {
            if (i < T_SZ) {
                const int pr = (i + 1) & 1, ps = i & 1;
                f16x8 ah[2], al[2];
                ah[0] = *(const f16x8*)&h0hi[pr][u][8 * kq];
                ah[1] = *(const f16x8*)&h0hi[pr][u][32 + 8 * kq];
                al[0] = *(const f16x8*)&h0lo[pr][u][8 * kq];
                al[1] = *(const f16x8*)&h0lo[pr][u][32 + 8 * kq];
                f32x4 aR = aR_nx, aZ = aZ_nx;
                f32x4 aN = {bHN0, bHN0, bHN0, bHN0};
                float xn0[4] = {xn_nx[0], xn_nx[1], xn_nx[2], xn_nx[3]};
                __builtin_amdgcn_s_setprio(1);
#pragma unroll
                for (int kk = 0; kk < 2; ++kk) {
                    aR = MFMA16(ah[kk], wR[kk], aR);
                    aZ = MFMA16(ah[kk], wZ[kk], aZ);
                    aN = MFMA16(ah[kk], wN[kk], aN);
                    aR = MFMA16(al[kk], wR[kk], aR);
                    aZ = MFMA16(al[kk], wZ[kk], aZ);
                    aN = MFMA16(al[kk], wN[kk], aN);
                }
                __builtin_amdgcn_s_setprio(0);
                // next step's x-path in the MFMA shadow
                if (i + 1 < T_SZ) {
                    float xv[20];
                    *(float4*)&xv[0]  = *(const float4*)&xst[i + 1][kq][0];
                    *(float4*)&xv[4]  = *(const float4*)&xst[i + 1][kq][4];
                    *(float4*)&xv[8]  = *(const float4*)&xst[i + 1][kq][8];
                    *(float4*)&xv[12] = *(const float4*)&xst[i + 1][kq][12];
                    *(float4*)&xv[16] = *(const float4*)&xst[i + 1][kq][16];
#pragma unroll
                    for (int r = 0; r < 4; ++r) {
                        float vR = bR0, vZ = bZ0, vN = bXN0;
#pragma unroll
                        for (int d = 0; d < 5; ++d) {
                            float x1 = xv[r * 5 + d];
                            vR = fmaf(wxr[d], x1, vR);
                            vZ = fmaf(wxz[d], x1, vZ);
                            vN = fmaf(wxn[d], x1, vN);
                        }
                        aR_nx[r] = vR; aZ_nx[r] = vZ; xn_nx[r] = vN;
                    }
                }
#pragma unroll
                for (int r = 0; r < 4; ++r) {
                    float ER = __builtin_amdgcn_exp2f(aR[r]);
                    float rg = __builtin_amdgcn_rcpf(1.0f + ER);
                    float w  = fmaf(rg, aN[r], xn0[r]);
                    float EN = __builtin_amdgcn_exp2f(w);
                    float n  = fmaf(2.0f, __builtin_amdgcn_rcpf(1.0f + EN), -1.0f);
                    float EZ = __builtin_amdgcn_exp2f(aZ[r]);
                    float hv = fmaf(EZ, h0_own[r], n) * __builtin_amdgcn_rcpf(1.0f + EZ);
                    h0_own[r] = hv;
                    _Float16 hi = (_Float16)hv;
                    _Float16 lo = (_Float16)(hv - (float)hi);
                    h0hi[ps][rbase + r][ug] = hi;
                    h0lo[ps][rbase + r][ug] = lo;
                }
            }
            __syncthreads();
        }
    } else if (grp == 1) {
        // =========== L1a: ih1 * h0(t), t = i-1 -> partials (prio 0) ===========
        f16x8 iR[2], iZ[2], iX[2];
#pragma unroll
        for (int kk = 0; kk < 2; ++kk) {
            const int kb = kk * 32 + 8 * kq;
            load_wfrag_hi(w_ih1, 0 * 64 + ug, kb, NLOG2E,  iR[kk]);
            load_wfrag_hi(w_ih1, 1 * 64 + ug, kb, PLOG2E,  iZ[kk]);
            load_wfrag_hi(w_ih1, 2 * 64 + ug, kb, N2LOG2E, iX[kk]);
        }
        const float bR1 = (b_ih1[ug] + b_hh1[ug]) * NLOG2E;
        const float bZ1 = (b_ih1[64 + ug] + b_hh1[64 + ug]) * PLOG2E;
        const float bX1 = b_ih1[128 + ug] * N2LOG2E;

        for (int i = 0; i <= T_SZ + 1; ++i) {
            if (i >= 1 && i <= T_SZ) {
                const int t = i - 1, st = t & 1;
                f16x8 ah[2], al[2];
                ah[0] = *(const f16x8*)&h0hi[st][u][8 * kq];
                ah[1] = *(const f16x8*)&h0hi[st][u][32 + 8 * kq];
                al[0] = *(const f16x8*)&h0lo[st][u][8 * kq];
                al[1] = *(const f16x8*)&h0lo[st][u][32 + 8 * kq];
                f32x4 qR = {bR1, bR1, bR1, bR1};
                f32x4 qZ = {bZ1, bZ1, bZ1, bZ1};
                f32x4 qX = {bX1, bX1, bX1, bX1};
#pragma unroll
                for (int kk = 0; kk < 2; ++kk) {
                    qR = MFMA16(ah[kk], iR[kk], qR);
                    qZ = MFMA16(ah[kk], iZ[kk], qZ);
                    qX = MFMA16(ah[kk], iX[kk], qX);
                    qR = MFMA16(al[kk], iR[kk], qR);
                    qZ = MFMA16(al[kk], iZ[kk], qZ);
                    qX = MFMA16(al[kk], iX[kk], qX);
                }
                *(f32x4*)&pP[st][0][ug][rbase] = qR;
                *(f32x4*)&pP[st][1][ug][rbase] = qZ;
                *(f32x4*)&pP[st][2][ug][rbase] = qX;
            }
            __syncthreads();
        }
    } else {
        // ====== L1b: hh1 * h1(t-1) + partials(t) + act, t = i-2 ======
        f16x8 hR[2], hZ[2], hN[2];
#pragma unroll
        for (int kk = 0; kk < 2; ++kk) {
            const int kb = kk * 32 + 8 * kq;
            load_wfrag_hi(w_hh1, 0 * 64 + ug, kb, NLOG2E,  hR[kk]);
            load_wfrag_hi(w_hh1, 1 * 64 + ug, kb, PLOG2E,  hZ[kk]);
            load_wfrag_hi(w_hh1, 2 * 64 + ug, kb, N2LOG2E, hN[kk]);
        }
        const float bN1 = b_hh1[128 + ug] * N2LOG2E;
        float h1_own[4] = {0.f, 0.f, 0.f, 0.f};

        for (int i = 0; i <= T_SZ + 1; ++i) {
            if (i >= 2) {
                const int t = i - 2, st = t & 1;
                f16x8 ah[2], al[2];                      // h1(t-1), slot st^1
                ah[0] = *(const f16x8*)&h1hi[st ^ 1][u][8 * kq];
                ah[1] = *(const f16x8*)&h1hi[st ^ 1][u][32 + 8 * kq];
                al[0] = *(const f16x8*)&h1lo[st ^ 1][u][8 * kq];
                al[1] = *(const f16x8*)&h1lo[st ^ 1][u][32 + 8 * kq];
                // prefetch partials (written last interval, ready now)
                const f32x4 qR = *(const f32x4*)&pP[st][0][ug][rbase];
                const f32x4 qZ = *(const f32x4*)&pP[st][1][ug][rbase];
                const f32x4 qX = *(const f32x4*)&pP[st][2][ug][rbase];
                f32x4 cR = {0.f, 0.f, 0.f, 0.f};
                f32x4 cZ = {0.f, 0.f, 0.f, 0.f};
                f32x4 cN = {bN1, bN1, bN1, bN1};
                __builtin_amdgcn_s_setprio(1);
#pragma unroll
                for (int kk = 0; kk < 2; ++kk) {
                    cR = MFMA16(ah[kk], hR[kk], cR);
                    cZ = MFMA16(ah[kk], hZ[kk], cZ);
                    cN = MFMA16(ah[kk], hN[kk], cN);
                    cR = MFMA16(al[kk], hR[kk], cR);
                    cZ = MFMA16(al[kk], hZ[kk], cZ);
                    cN = MFMA16(al[kk], hN[kk], cN);
                }
                __builtin_amdgcn_s_setprio(0);
#pragma unroll
                for (int r = 0; r < 4; ++r) {
                    float ER = __builtin_amdgcn_exp2f(cR[r] + qR[r]);
                    float rg = __builtin_amdgcn_rcpf(1.0f + ER);
                    float w  = fmaf(rg, cN[r], qX[r]);
                    float EN = __builtin_amdgcn_exp2f(w);
                    float n  = fmaf(2.0f, __builtin_amdgcn_rcpf(1.0f + EN), -1.0f);
                    float EZ = __builtin_amdgcn_exp2f(cZ[r] + qZ[r]);
                    float hv = fmaf(EZ, h1_own[r], n) * __builtin_amdgcn_rcpf(1.0f + EZ);
                    h1_own[r] = hv;
                    _Float16 hi = (_Float16)hv;
                    _Float16 lo = (_Float16)(hv - (float)hi);
                    h1hi[st][rbase + r][ug] = hi;
                    h1lo[st][rbase + r][ug] = lo;
                }
            }
            __syncthreads();
        }
    }

    // ---- FC epilogue: h1(255) in slot 255&1 = 1 ----
    if (tid < 16) {
        float s = fc_b[0];
#pragma unroll 1
        for (int uu = 0; uu < 64; ++uu)
            s = fmaf(fc_w[uu], (float)h1hi[1][tid][uu] + (float)h1lo[1][tid][uu], s);
        out[blockIdx.x * 16 + tid] = s;
    }
}

extern "C" void kernel_launch(void* const* d_in, const int* in_sizes, int n_in,
                              void* d_out, int out_size, void* d_ws, size_t ws_size,
                              hipStream_t stream) {
    const float* x     = (const float*)d_in[0];
    const float* w_ih0 = (const float*)d_in[1];
    const float* w_hh0 = (const float*)d_in[2];
    const float* b_ih0 = (const float*)d_in[3];
    const float* b_hh0 = (const float*)d_in[4];
    const float* w_ih1 = (const float*)d_in[5];
    const float* w_hh1 = (const float*)d_in[6];
    const float* b_ih1 = (const float*)d_in[7];
    const float* b_hh1 = (const float*)d_in[8];
    const float* fc_w  = (const float*)d_in[9];
    const float* fc_b  = (const float*)d_in[10];
    float* out = (float*)d_out;

    gru2_f16<<<dim3(256), dim3(768), 0, stream>>>(x, w_ih0, w_hh0, b_ih0, b_hh0,
                                                  w_ih1, w_hh1, b_ih1, b_hh1,
                                                  fc_w, fc_b, out);
}